// Round 1
// baseline (155.967 us; speedup 1.0000x reference)
//
#include <hip/hip_runtime.h>

#define K_POI  10
#define V_POI  11
#define E_DIM  128
#define ALPHA  0.9f

// Kernel 1: per-location fused result table.
// table[p][e] = emb_loc[p][e]*ALPHA + (sum_k exp(w)^2 / sum_k exp(w)) * (1-ALPHA)
// One block per location p, one thread per embedding dim e.
__global__ void build_table_kernel(const int* __restrict__ poi_table,
                                   const float* __restrict__ emb_poi,
                                   const float* __restrict__ emb_loc,
                                   float* __restrict__ table) {
    const int p = blockIdx.x;
    const int e = threadIdx.x;

    float s = 0.0f, s2 = 0.0f;
#pragma unroll
    for (int k = 0; k < K_POI; ++k) {
        // wave-uniform -> scalar load
        const int cat = poi_table[p * K_POI + k];
        const float w = emb_poi[cat * E_DIM + e];
        const float pe = expf(w);
        s  += pe;
        s2 += pe * pe;
    }
    const float poi = s2 / s;
    table[p * E_DIM + e] = emb_loc[p * E_DIM + e] * ALPHA + poi * (1.0f - ALPHA);
}

// Kernel 2: pure row gather, float4-vectorized.
// thread t -> output row t>>5, float4 index t&31 (128 floats = 32 float4 per row)
__global__ void gather_kernel(const int* __restrict__ x,
                              const float4* __restrict__ table4,
                              float4* __restrict__ out4,
                              int total4) {
    const int stride = gridDim.x * blockDim.x;
    for (int t = blockIdx.x * blockDim.x + threadIdx.x; t < total4; t += stride) {
        const int row = t >> 5;
        const int q   = t & 31;
        const int xi  = x[row];
        out4[t] = table4[(size_t)xi * 32 + q];
    }
}

// Fallback (only if ws_size is too small for the table): direct compute with
// exp tables staged in LDS (V*E floats, 5.5 KB) — no per-element expf.
__global__ void direct_kernel(const int* __restrict__ x,
                              const int* __restrict__ poi_table,
                              const float* __restrict__ emb_poi,
                              const float* __restrict__ emb_loc,
                              float* __restrict__ out,
                              int n) {
    __shared__ float sh_exp[V_POI * E_DIM];
    for (int i = threadIdx.x; i < V_POI * E_DIM; i += blockDim.x)
        sh_exp[i] = expf(emb_poi[i]);
    __syncthreads();

    const int stride = gridDim.x * blockDim.x;
    const int total = n * E_DIM;
    for (int t = blockIdx.x * blockDim.x + threadIdx.x; t < total; t += stride) {
        const int row = t >> 7;          // / E_DIM
        const int e   = t & (E_DIM - 1);
        const int xi  = x[row];
        float s = 0.0f, s2 = 0.0f;
#pragma unroll
        for (int k = 0; k < K_POI; ++k) {
            const int cat = poi_table[xi * K_POI + k];
            const float pe = sh_exp[cat * E_DIM + e];
            s  += pe;
            s2 += pe * pe;
        }
        out[t] = emb_loc[(size_t)xi * E_DIM + e] * ALPHA + (s2 / s) * (1.0f - ALPHA);
    }
}

extern "C" void kernel_launch(void* const* d_in, const int* in_sizes, int n_in,
                              void* d_out, int out_size, void* d_ws, size_t ws_size,
                              hipStream_t stream) {
    const int*   x        = (const int*)d_in[0];
    const int*   poi_tab  = (const int*)d_in[1];
    const float* emb_poi  = (const float*)d_in[2];
    const float* emb_loc  = (const float*)d_in[3];
    float*       out      = (float*)d_out;

    const int n = in_sizes[0];                 // number of location ids (N)
    const int P = in_sizes[1] / K_POI;         // point_size (rows of poi table)

    const size_t table_bytes = (size_t)P * E_DIM * sizeof(float);

    if (ws_size >= table_bytes) {
        float* table = (float*)d_ws;
        build_table_kernel<<<P, E_DIM, 0, stream>>>(poi_tab, emb_poi, emb_loc, table);
        const int total4 = n * (E_DIM / 4);
        gather_kernel<<<2048, 256, 0, stream>>>(x, (const float4*)table,
                                                (float4*)out, total4);
    } else {
        direct_kernel<<<2048, 256, 0, stream>>>(x, poi_tab, emb_poi, emb_loc, out, n);
    }
}

// Round 5
// 154.947 us; speedup vs baseline: 1.0066x; 1.0066x over previous
//
#include <hip/hip_runtime.h>

#define K_POI  10
#define V_POI  11
#define E_DIM  128
#define ALPHA  0.9f

// native clang vector type: accepted by __builtin_nontemporal_store
// (HIP_vector_type float4 is a struct and is rejected).
typedef float f32x4 __attribute__((ext_vector_type(4)));

// Kernel 1: per-location fused result table (P=2500 rows only).
// table[p][e] = emb_loc[p][e]*ALPHA + (sum_k exp(w)^2 / sum_k exp(w)) * (1-ALPHA)
// One block per location p, one thread per embedding dim e. poi_table reads are
// block-uniform -> scalar loads. ~3 us total, not the bottleneck.
__global__ __launch_bounds__(128) void build_table_kernel(
        const int* __restrict__ poi_table,
        const float* __restrict__ emb_poi,
        const float* __restrict__ emb_loc,
        float* __restrict__ table) {
    const int p = blockIdx.x;
    const int e = threadIdx.x;

    float s = 0.0f, s2 = 0.0f;
#pragma unroll
    for (int k = 0; k < K_POI; ++k) {
        const int cat = poi_table[p * K_POI + k];
        const float w = emb_poi[cat * E_DIM + e];
        const float pe = expf(w);
        s  += pe;
        s2 += pe * pe;
    }
    const float poi = s2 / s;
    table[p * E_DIM + e] = emb_loc[p * E_DIM + e] * ALPHA + poi * (1.0f - ALPHA);
}

// Kernel 2: row gather with 4-way ILP per thread.
// 8 threads per output row; thread owns float4 quads q, q+8, q+16, q+24 of its
// row. Straight-line: 1 x-load, then 4 INDEPENDENT table loads (shared base
// address + offset immediates), 4 nontemporal stores. No grid-stride loop.
__global__ __launch_bounds__(256) void gather_kernel(
        const int* __restrict__ x,
        const f32x4* __restrict__ table4,
        f32x4* __restrict__ out4,
        int nrows) {
    const int t = blockIdx.x * 256 + threadIdx.x;
    const int row = t >> 3;
    if (row >= nrows) return;
    const int q = t & 7;

    const int xi = x[row];                       // L2-hot after first touch
    const f32x4* __restrict__ src = table4 + xi * 32 + q;    // 32-bit index math
    f32x4* __restrict__ dst = out4 + (size_t)row * 32 + q;

    const f32x4 a = src[0];
    const f32x4 b = src[8];
    const f32x4 c = src[16];
    const f32x4 d = src[24];
    __builtin_nontemporal_store(a, dst + 0);     // streaming: out never re-read
    __builtin_nontemporal_store(b, dst + 8);
    __builtin_nontemporal_store(c, dst + 16);
    __builtin_nontemporal_store(d, dst + 24);
}

// Fallback (only if ws_size can't hold the table): direct compute with the
// exp(emb_poi) table staged in LDS.
__global__ void direct_kernel(const int* __restrict__ x,
                              const int* __restrict__ poi_table,
                              const float* __restrict__ emb_poi,
                              const float* __restrict__ emb_loc,
                              float* __restrict__ out,
                              int n) {
    __shared__ float sh_exp[V_POI * E_DIM];
    for (int i = threadIdx.x; i < V_POI * E_DIM; i += blockDim.x)
        sh_exp[i] = expf(emb_poi[i]);
    __syncthreads();

    const int stride = gridDim.x * blockDim.x;
    const int total = n * E_DIM;
    for (int t = blockIdx.x * blockDim.x + threadIdx.x; t < total; t += stride) {
        const int row = t >> 7;
        const int e   = t & (E_DIM - 1);
        const int xi  = x[row];
        float s = 0.0f, s2 = 0.0f;
#pragma unroll
        for (int k = 0; k < K_POI; ++k) {
            const int cat = poi_table[xi * K_POI + k];
            const float pe = sh_exp[cat * E_DIM + e];
            s  += pe;
            s2 += pe * pe;
        }
        out[t] = emb_loc[(size_t)xi * E_DIM + e] * ALPHA + (s2 / s) * (1.0f - ALPHA);
    }
}

extern "C" void kernel_launch(void* const* d_in, const int* in_sizes, int n_in,
                              void* d_out, int out_size, void* d_ws, size_t ws_size,
                              hipStream_t stream) {
    const int*   x        = (const int*)d_in[0];
    const int*   poi_tab  = (const int*)d_in[1];
    const float* emb_poi  = (const float*)d_in[2];
    const float* emb_loc  = (const float*)d_in[3];
    float*       out      = (float*)d_out;

    const int n = in_sizes[0];                 // N location ids
    const int P = in_sizes[1] / K_POI;         // point_size

    const size_t table_bytes = (size_t)P * E_DIM * sizeof(float);

    if (ws_size >= table_bytes) {
        float* table = (float*)d_ws;
        build_table_kernel<<<P, E_DIM, 0, stream>>>(poi_tab, emb_poi, emb_loc, table);
        const int nthreads = n * 8;            // 8 threads per row
        gather_kernel<<<(nthreads + 255) / 256, 256, 0, stream>>>(
            x, (const f32x4*)table, (f32x4*)out, n);
    } else {
        direct_kernel<<<2048, 256, 0, stream>>>(x, poi_tab, emb_poi, emb_loc, out, n);
    }
}

// Round 9
// 151.153 us; speedup vs baseline: 1.0318x; 1.0251x over previous
//
#include <hip/hip_runtime.h>

#define K_POI  10
#define V_POI  11
#define E_DIM  128
#define ALPHA  0.9f

// native clang vector type: accepted by __builtin_nontemporal_store
// (HIP_vector_type float4 is a struct and is rejected).
typedef float f32x4 __attribute__((ext_vector_type(4)));

// Kernel 1: per-location fused result table (P=2500 rows only).
// table[p][e] = emb_loc[p][e]*ALPHA + (sum_k exp(w)^2 / sum_k exp(w)) * (1-ALPHA)
// One block per location p, one thread per embedding dim e. poi_table reads are
// block-uniform -> scalar loads. ~3 us total, not the bottleneck.
__global__ __launch_bounds__(128) void build_table_kernel(
        const int* __restrict__ poi_table,
        const float* __restrict__ emb_poi,
        const float* __restrict__ emb_loc,
        float* __restrict__ table) {
    const int p = blockIdx.x;
    const int e = threadIdx.x;

    float s = 0.0f, s2 = 0.0f;
#pragma unroll
    for (int k = 0; k < K_POI; ++k) {
        const int cat = poi_table[p * K_POI + k];
        const float w = emb_poi[cat * E_DIM + e];
        const float pe = expf(w);
        s  += pe;
        s2 += pe * pe;
    }
    const float poi = s2 / s;
    table[p * E_DIM + e] = emb_loc[p * E_DIM + e] * ALPHA + poi * (1.0f - ALPHA);
}

// Kernel 2: row gather, 2 rows per thread, 8-way MLP.
// 8 threads per row-slot; thread owns float4 quads q, q+8, q+16, q+24 of rows
// r and r+half. 2 independent x-loads, then 8 INDEPENDENT table loads, then
// 8 nontemporal stores. Probe: if this doesn't move dur_us vs the 4-way
// version, the kernel is at the write-BW floor / harness-overhead-dominated.
__global__ __launch_bounds__(256) void gather_kernel(
        const int* __restrict__ x,
        const f32x4* __restrict__ table4,
        f32x4* __restrict__ out4,
        int nrows, int half) {
    const int t = blockIdx.x * 256 + threadIdx.x;
    const int r0 = t >> 3;
    if (r0 >= half) return;
    const int q = t & 7;
    const int r1 = r0 + half;
    const bool has2 = (r1 < nrows);

    const int xi0 = x[r0];
    const int xi1 = has2 ? x[r1] : 0;

    const f32x4* __restrict__ src0 = table4 + xi0 * 32 + q;
    const f32x4* __restrict__ src1 = table4 + xi1 * 32 + q;

    const f32x4 a0 = src0[0];
    const f32x4 b0 = src0[8];
    const f32x4 c0 = src0[16];
    const f32x4 d0 = src0[24];
    const f32x4 a1 = src1[0];
    const f32x4 b1 = src1[8];
    const f32x4 c1 = src1[16];
    const f32x4 d1 = src1[24];

    f32x4* __restrict__ dst0 = out4 + (size_t)r0 * 32 + q;
    __builtin_nontemporal_store(a0, dst0 + 0);
    __builtin_nontemporal_store(b0, dst0 + 8);
    __builtin_nontemporal_store(c0, dst0 + 16);
    __builtin_nontemporal_store(d0, dst0 + 24);
    if (has2) {
        f32x4* __restrict__ dst1 = out4 + (size_t)r1 * 32 + q;
        __builtin_nontemporal_store(a1, dst1 + 0);
        __builtin_nontemporal_store(b1, dst1 + 8);
        __builtin_nontemporal_store(c1, dst1 + 16);
        __builtin_nontemporal_store(d1, dst1 + 24);
    }
}

// Fallback (only if ws_size can't hold the table): direct compute with the
// exp(emb_poi) table staged in LDS.
__global__ void direct_kernel(const int* __restrict__ x,
                              const int* __restrict__ poi_table,
                              const float* __restrict__ emb_poi,
                              const float* __restrict__ emb_loc,
                              float* __restrict__ out,
                              int n) {
    __shared__ float sh_exp[V_POI * E_DIM];
    for (int i = threadIdx.x; i < V_POI * E_DIM; i += blockDim.x)
        sh_exp[i] = expf(emb_poi[i]);
    __syncthreads();

    const int stride = gridDim.x * blockDim.x;
    const int total = n * E_DIM;
    for (int t = blockIdx.x * blockDim.x + threadIdx.x; t < total; t += stride) {
        const int row = t >> 7;
        const int e   = t & (E_DIM - 1);
        const int xi  = x[row];
        float s = 0.0f, s2 = 0.0f;
#pragma unroll
        for (int k = 0; k < K_POI; ++k) {
            const int cat = poi_table[xi * K_POI + k];
            const float pe = sh_exp[cat * E_DIM + e];
            s  += pe;
            s2 += pe * pe;
        }
        out[t] = emb_loc[(size_t)xi * E_DIM + e] * ALPHA + (s2 / s) * (1.0f - ALPHA);
    }
}

extern "C" void kernel_launch(void* const* d_in, const int* in_sizes, int n_in,
                              void* d_out, int out_size, void* d_ws, size_t ws_size,
                              hipStream_t stream) {
    const int*   x        = (const int*)d_in[0];
    const int*   poi_tab  = (const int*)d_in[1];
    const float* emb_poi  = (const float*)d_in[2];
    const float* emb_loc  = (const float*)d_in[3];
    float*       out      = (float*)d_out;

    const int n = in_sizes[0];                 // N location ids
    const int P = in_sizes[1] / K_POI;         // point_size

    const size_t table_bytes = (size_t)P * E_DIM * sizeof(float);

    if (ws_size >= table_bytes) {
        float* table = (float*)d_ws;
        build_table_kernel<<<P, E_DIM, 0, stream>>>(poi_tab, emb_poi, emb_loc, table);
        const int half = (n + 1) >> 1;
        const int nthreads = half * 8;         // 8 threads per row-slot, 2 rows each
        gather_kernel<<<(nthreads + 255) / 256, 256, 0, stream>>>(
            x, (const f32x4*)table, (f32x4*)out, n, half);
    } else {
        direct_kernel<<<2048, 256, 0, stream>>>(x, poi_tab, emb_poi, emb_loc, out, n);
    }
}